// Round 1
// baseline (387.675 us; speedup 1.0000x reference)
//
#include <hip/hip_runtime.h>
#include <math.h>

// Workspace layout (floats):
#define W2OFF  0        // 8192: W2[e][d] = sum_o key[e][o]*Wq[o][d]
#define B2OFF  8192     // 8:    b2[e]    = sum_d bq[d]*key[e][d]
#define SCOFF  8200     // 512:  score sums [batch][e] (sum over s of softmax w)
#define AUXOFF 8712     // 1:    sum of w*log(w+1e-9)
#define ZCNT   513      // floats to zero starting at SCOFF

// ---------------- k0: zero accumulators + bias term ----------------
__global__ __launch_bounds__(256) void k0_prep(const float* __restrict__ bq,
                                               const float* __restrict__ key,
                                               float* __restrict__ ws) {
    __shared__ float part[256 * 8];
    int tid = threadIdx.x;
    #pragma unroll
    for (int k = 0; k < 3; ++k) {
        int i = tid + 256 * k;
        if (i < ZCNT) ws[SCOFF + i] = 0.0f;
    }
    float p[8];
    #pragma unroll
    for (int e = 0; e < 8; ++e) p[e] = 0.0f;
    #pragma unroll
    for (int k = 0; k < 4; ++k) {
        int d = tid + 256 * k;
        float bv = bq[d];
        #pragma unroll
        for (int e = 0; e < 8; ++e) p[e] += bv * key[e * 1024 + d];
    }
    #pragma unroll
    for (int e = 0; e < 8; ++e) part[tid * 8 + e] = p[e];
    __syncthreads();
    if (tid < 8) {
        float s = 0.0f;
        for (int k = 0; k < 256; ++k) s += part[k * 8 + tid];
        ws[B2OFF + tid] = s;
    }
}

// ---------------- k1: W2 = key_emb @ Wq  (8x1024 @ 1024x1024) ----------------
// 64 blocks, each owns 16 output columns d; 16 o-groups of 64 per block.
__global__ __launch_bounds__(256) void k1_w2(const float* __restrict__ Wq,
                                             const float* __restrict__ key,
                                             float* __restrict__ ws) {
    __shared__ __attribute__((aligned(16))) float keyl[8 * 1024];  // 32 KB
    __shared__ float part[256 * 8];                                // 8 KB
    int tid = threadIdx.x;
    int blk = blockIdx.x;

    float4* kl4 = (float4*)keyl;
    const float4* kg4 = (const float4*)key;
    #pragma unroll
    for (int k = 0; k < 8; ++k) kl4[tid + 256 * k] = kg4[tid + 256 * k];
    __syncthreads();

    int dl = tid & 15;
    int og = tid >> 4;            // 16 o-groups x 64 o's
    int d  = blk * 16 + dl;
    float acc[8];
    #pragma unroll
    for (int e = 0; e < 8; ++e) acc[e] = 0.0f;
    for (int oo = 0; oo < 64; ++oo) {
        int o = og * 64 + oo;
        float wv = Wq[o * 1024 + d];
        #pragma unroll
        for (int e = 0; e < 8; ++e) acc[e] += keyl[e * 1024 + o] * wv;
    }
    #pragma unroll
    for (int e = 0; e < 8; ++e) part[tid * 8 + e] = acc[e];
    __syncthreads();
    if (tid < 128) {
        int dl2 = tid >> 3, e = tid & 7;
        float s = 0.0f;
        #pragma unroll
        for (int g = 0; g < 16; ++g) s += part[(g * 16 + dl2) * 8 + e];
        ws[W2OFF + e * 1024 + blk * 16 + dl2] = s;
    }
}

// ---------------- k2: main streaming pass over x ----------------
// 1024 blocks x 256 thr; block handles 64 consecutive tokens of one batch.
// Wave processes 4 tokens per pass (W2 LDS reads amortized x4).
__global__ __launch_bounds__(256) void k2_main(const float* __restrict__ x,
                                               float* __restrict__ ws) {
    __shared__ __attribute__((aligned(16))) float w2l[8 * 1024];   // 32 KB
    __shared__ __attribute__((aligned(16))) float part[4 * 64 * 8]; // 8 KB, per-wave [64][8]
    __shared__ __attribute__((aligned(16))) float sraw[64 * 8];     // 2 KB raw scores

    int tid  = threadIdx.x;
    int blk  = blockIdx.x;           // 1024 blocks
    int lane = tid & 63;
    int w    = tid >> 6;             // wave 0..3
    int batch = blk >> 4;
    int tb    = blk * 64;            // global token base

    // stage W2 into LDS
    float4* wl4 = (float4*)w2l;
    const float4* wg4 = (const float4*)(ws + W2OFF);
    #pragma unroll
    for (int k = 0; k < 8; ++k) wl4[tid + 256 * k] = wg4[tid + 256 * k];
    __syncthreads();

    const float4* x4 = (const float4*)x;
    float* pw = part + w * 512;      // this wave's [64][8] scratch

    for (int p = 0; p < 4; ++p) {
        int lt0 = w * 16 + p * 4;    // local token base (0..63)
        int t0  = tb + lt0;
        float acc[4][8];
        #pragma unroll
        for (int j = 0; j < 4; ++j)
            #pragma unroll
            for (int e = 0; e < 8; ++e) acc[j][e] = 0.0f;

        #pragma unroll
        for (int i = 0; i < 4; ++i) {
            float4 xr[4];
            #pragma unroll
            for (int j = 0; j < 4; ++j)
                xr[j] = x4[(size_t)(t0 + j) * 256 + i * 64 + lane];
            #pragma unroll
            for (int e = 0; e < 8; ++e) {
                float4 w4 = wl4[e * 256 + i * 64 + lane];
                #pragma unroll
                for (int j = 0; j < 4; ++j)
                    acc[j][e] += w4.x * xr[j].x + w4.y * xr[j].y +
                                 w4.z * xr[j].z + w4.w * xr[j].w;
            }
        }

        // per-token cross-lane reduction via LDS transpose (wave-internal)
        #pragma unroll
        for (int j = 0; j < 4; ++j) {
            float4* pw4 = (float4*)(pw + lane * 8);
            pw4[0] = make_float4(acc[j][0], acc[j][1], acc[j][2], acc[j][3]);
            pw4[1] = make_float4(acc[j][4], acc[j][5], acc[j][6], acc[j][7]);
            int e = lane >> 3, r = lane & 7;
            float s = 0.0f;
            #pragma unroll
            for (int m = 0; m < 8; ++m) s += pw[(r + m * 8) * 8 + e];
            s += __shfl_xor(s, 1);
            s += __shfl_xor(s, 2);
            s += __shfl_xor(s, 4);
            if (r == 0) sraw[(lt0 + j) * 8 + e] = s;
        }
    }
    __syncthreads();

    // Phase B: 64 lanes (wave 0), one token each: softmax + aux + score sums
    if (tid < 64) {
        float4 a = ((float4*)sraw)[tid * 2];
        float4 b = ((float4*)sraw)[tid * 2 + 1];
        float s[8] = {a.x, a.y, a.z, a.w, b.x, b.y, b.z, b.w};
        const float scale = 0.03125f;  // 1024^-0.5
        #pragma unroll
        for (int e = 0; e < 8; ++e) s[e] = (s[e] + ws[B2OFF + e]) * scale;
        float mx = s[0];
        #pragma unroll
        for (int e = 1; e < 8; ++e) mx = fmaxf(mx, s[e]);
        float wgt[8], sum = 0.0f;
        #pragma unroll
        for (int e = 0; e < 8; ++e) { wgt[e] = expf(s[e] - mx); sum += wgt[e]; }
        float inv = 1.0f / sum;
        float aux = 0.0f;
        #pragma unroll
        for (int e = 0; e < 8; ++e) {
            wgt[e] *= inv;
            aux += wgt[e] * logf(wgt[e] + 1e-9f);
        }
        // block score-sum reduction (these 64 threads are wave 0)
        float* pw0 = part;
        float4* q4 = (float4*)(pw0 + tid * 8);
        q4[0] = make_float4(wgt[0], wgt[1], wgt[2], wgt[3]);
        q4[1] = make_float4(wgt[4], wgt[5], wgt[6], wgt[7]);
        int e = tid >> 3, r = tid & 7;
        float s2 = 0.0f;
        #pragma unroll
        for (int m = 0; m < 8; ++m) s2 += pw0[(r + m * 8) * 8 + e];
        s2 += __shfl_xor(s2, 1);
        s2 += __shfl_xor(s2, 2);
        s2 += __shfl_xor(s2, 4);
        if (r == 0) atomicAdd(&ws[SCOFF + batch * 8 + e], s2);
        // aux reduction across 64 lanes
        aux += __shfl_xor(aux, 1);
        aux += __shfl_xor(aux, 2);
        aux += __shfl_xor(aux, 4);
        aux += __shfl_xor(aux, 8);
        aux += __shfl_xor(aux, 16);
        aux += __shfl_xor(aux, 32);
        if (tid == 0) atomicAdd(&ws[AUXOFF], aux);
    }
}

// ---------------- k3: top-2, mask broadcast, indices, loss ----------------
__device__ __forceinline__ void top2_of8(const float* v, int& i1, int& i2) {
    i1 = 0; float b1 = v[0];
    #pragma unroll
    for (int e = 1; e < 8; ++e) if (v[e] > b1) { b1 = v[e]; i1 = e; }
    i2 = -1; float b2 = -3.4e38f;
    #pragma unroll
    for (int e = 0; e < 8; ++e) if (e != i1 && v[e] > b2) { b2 = v[e]; i2 = e; }
}

__global__ __launch_bounds__(256) void k3_out(const float* __restrict__ ws,
                                              float* __restrict__ out) {
    int tid = threadIdx.x;
    int blk = blockIdx.x;            // 256 blocks; 4 per batch
    int batch = blk >> 2;

    float v[8];
    #pragma unroll
    for (int e = 0; e < 8; ++e) v[e] = ws[SCOFF + batch * 8 + e];
    int i1, i2;
    top2_of8(v, i1, i2);

    float m[8];
    #pragma unroll
    for (int e = 0; e < 8; ++e) m[e] = (e == i1 || e == i2) ? 1.0f : 0.0f;
    int token = blk * 256 + tid;
    float4* o4 = (float4*)out;
    o4[token * 2]     = make_float4(m[0], m[1], m[2], m[3]);
    o4[token * 2 + 1] = make_float4(m[4], m[5], m[6], m[7]);

    if (blk == 0) {
        __shared__ int cnt[8];
        if (tid < 8) cnt[tid] = 0;
        __syncthreads();
        if (tid < 64) {
            float vv[8];
            #pragma unroll
            for (int e = 0; e < 8; ++e) vv[e] = ws[SCOFF + tid * 8 + e];
            int j1, j2;
            top2_of8(vv, j1, j2);
            out[524288 + tid * 2]     = (float)j1;
            out[524288 + tid * 2 + 1] = (float)j2;
            atomicAdd(&cnt[j1], 1);
            atomicAdd(&cnt[j2], 1);
        }
        __syncthreads();
        if (tid == 0) {
            float kl = 0.0f;
            #pragma unroll
            for (int e = 0; e < 8; ++e) {
                float usage = (float)cnt[e] / 64.0f;
                kl += 0.125f * (logf(0.125f) - logf(usage));
            }
            kl *= 0.125f;  // / E (batchmean)
            float aux = ws[AUXOFF] / 524288.0f;
            out[524416] = 1e-3f * kl + 1e-3f * aux;
        }
    }
}

extern "C" void kernel_launch(void* const* d_in, const int* in_sizes, int n_in,
                              void* d_out, int out_size, void* d_ws, size_t ws_size,
                              hipStream_t stream) {
    const float* x   = (const float*)d_in[0];
    const float* Wq  = (const float*)d_in[1];
    const float* bq  = (const float*)d_in[2];
    const float* key = (const float*)d_in[3];
    float* out = (float*)d_out;
    float* ws  = (float*)d_ws;

    k0_prep<<<1,    256, 0, stream>>>(bq, key, ws);
    k1_w2  <<<64,   256, 0, stream>>>(Wq, key, ws);
    k2_main<<<1024, 256, 0, stream>>>(x, ws);
    k3_out <<<256,  256, 0, stream>>>(ws, out);
}